// Round 5
// baseline (314.675 us; speedup 1.0000x reference)
//
#include <hip/hip_runtime.h>
#include <hip/hip_bf16.h>
#include <cstdint>

#define B_DIM 8192
#define N_DIM 64
#define C_DIM 16
#define D_DIM 1024
#define NUM 32
#define NCAUSAL 16
#define K_RANGES 8
#define HS 1024
#define HP 1024
#define TAU 0.7f
#define SMOOTH 0.1f

typedef __bf16 bf16x8 __attribute__((ext_vector_type(8)));
typedef float f32x16 __attribute__((ext_vector_type(16)));

typedef const __attribute__((address_space(1))) uint32_t* gas_ptr;
typedef __attribute__((address_space(3))) uint32_t* las_ptr;

__device__ __forceinline__ void gld_lds16(const void* g, void* l) {
    __builtin_amdgcn_global_load_lds((gas_ptr)(uintptr_t)g,
                                     (las_ptr)(uint32_t)(uintptr_t)l,
                                     16, 0, 0);
}

__device__ __forceinline__ int swz(int r) { return (r & 3) ^ ((r >> 2) & 3); }

// bijective XCD swizzle (all grids here have nwg % 8 == 0)
__device__ __forceinline__ void xcd_remap(int& bx, int& by)
{
    int gx  = gridDim.x;
    int nwg = gx * gridDim.y;
    int lin = by * gx + bx;
    int cpx = nwg >> 3;
    int sw  = (lin & 7) * cpx + (lin >> 3);
    by = sw / gx;
    bx = sw - by * gx;
}

// ---------------------------------------------------------------------------
// 8-wave 128x128 GEMM body — R3-proven protocol verbatim (BK=32, 2-buf LDS,
// one __syncthreads per K-step, swz chunk swizzle, absmax 0.015625).
// Occupancy experiment: launch_bounds minWavesPerEU raised 4 -> 8; at
// VGPR=40 / LDS=32KB the HW can hold 4 blocks x 8 waves = 32 waves/CU.
// Occupancy has tracked the launch_bounds declaration all session (20% at
// (256,2), ~50% at (512,4)) — this tests whether it was the cap.
// ACT: 0 = none (f32 out), 1 = relu (bf16 out), 2 = sigmoid (f32 out)
// ---------------------------------------------------------------------------
template <int ACT>
__device__ __forceinline__ void gemm_body8(
    const ushort* __restrict__ Ag, const ushort* __restrict__ Bg,
    const float* __restrict__ bias,
    float* __restrict__ Cf, __hip_bfloat16* __restrict__ Cb,
    int lda, int Nout, int ldC, int K, long m0, long n0,
    uint4 (*As)[512], uint4 (*Bs)[512])
{
    const int tid  = threadIdx.x;
    const int wave = tid >> 6;
    const int ln31 = tid & 31, blk = (tid >> 5) & 1;
    const int wr = wave >> 2, wc = wave & 3;

    const int row = tid >> 2;
    const int ch  = (tid & 3) ^ swz(row);
    const ushort* aSrc = Ag + (m0 + row) * (long)lda + ch * 8;
    const ushort* bSrc = Bg + (n0 + row) * (long)K   + ch * 8;
    const int ldsOff = wave << 6;   // wave-uniform LDS base

    f32x16 acc[2];
    acc[0] = (f32x16)(0.0f);
    acc[1] = (f32x16)(0.0f);

#define ISSUE_STAGE8(buf, kt)                                                  \
    {                                                                          \
        gld_lds16(aSrc + (kt), &As[buf][ldsOff]);                              \
        gld_lds16(bSrc + (kt), &Bs[buf][ldsOff]);                              \
    }

    ISSUE_STAGE8(0, 0);
    int cur = 0;
    for (int kt = 0; kt < K; kt += 32) {
        __syncthreads();   // drains vmcnt(0): buf 'cur' staged, prev reads done
        if (kt + 32 < K) ISSUE_STAGE8(cur ^ 1, kt + 32);

        bf16x8 af[2][2], bfr[2];
#pragma unroll
        for (int ks = 0; ks < 2; ++ks) {
            int c = ks * 2 + blk;
#pragma unroll
            for (int mi = 0; mi < 2; ++mi) {
                int r = wr * 64 + mi * 32 + ln31;
                af[ks][mi] = __builtin_bit_cast(bf16x8, As[cur][r * 4 + (c ^ swz(r))]);
            }
            int n = wc * 32 + ln31;
            bfr[ks] = __builtin_bit_cast(bf16x8, Bs[cur][n * 4 + (c ^ swz(n))]);
        }
#pragma unroll
        for (int ks = 0; ks < 2; ++ks)
#pragma unroll
            for (int mi = 0; mi < 2; ++mi)
                acc[mi] = __builtin_amdgcn_mfma_f32_32x32x16_bf16(
                    af[ks][mi], bfr[ks], acc[mi], 0, 0, 0);
        cur ^= 1;
    }
#undef ISSUE_STAGE8

    long col = n0 + wc * 32 + ln31;
    if (col < Nout) {
        float bs = bias ? bias[col] : 0.0f;
#pragma unroll
        for (int mi = 0; mi < 2; ++mi) {
#pragma unroll
            for (int reg = 0; reg < 16; ++reg) {
                long r2 = m0 + wr * 64 + mi * 32 + (reg & 3) + 8 * (reg >> 2) + 4 * blk;
                float v = acc[mi][reg] + bs;
                if (ACT == 1) {
                    v = fmaxf(v, 0.0f);
                    Cb[r2 * (long)ldC + col] = __float2bfloat16(v);
                } else if (ACT == 2) {
                    v = 1.0f / (1.0f + __expf(-v));
                    Cf[r2 * (long)ldC + col] = v;
                } else {
                    Cf[r2 * (long)ldC + col] = v;
                }
            }
        }
    }
}

// ---------------------------------------------------------------------------
// 4-wave 128x64 GEMM body — same wave tile (64x32), same fragment math,
// same accumulation order, same epilogue; 256 threads. Purpose: p-layers
// (N=1024) only yield 512 blocks at 128x128 -> grid-capped at 2 blocks/CU.
// 128x64 tiles give 1024+ blocks; 24KB LDS + (256,8) -> 6 blocks x 4 waves
// = 24 waves/CU.
// ---------------------------------------------------------------------------
template <int ACT>
__device__ __forceinline__ void gemm_body4(
    const ushort* __restrict__ Ag, const ushort* __restrict__ Bg,
    const float* __restrict__ bias,
    float* __restrict__ Cf, __hip_bfloat16* __restrict__ Cb,
    int lda, int Nout, int ldC, int K, long m0, long n0,
    uint4 (*As)[512], uint4 (*Bs)[256])
{
    const int tid  = threadIdx.x;
    const int wave = tid >> 6;
    const int ln31 = tid & 31, blk = (tid >> 5) & 1;
    const int wr = (wave >> 1) & 1, wc = wave & 1;

    // staging: A 512 slots (2 loads/thread), B 256 slots (1 load/thread)
    const int r0  = tid >> 2;
    const int ch0 = (tid & 3) ^ swz(r0);
    const int r1  = 64 + r0;
    const int ch1 = (tid & 3) ^ swz(r1);
    const ushort* aSrc0 = Ag + (m0 + r0) * (long)lda + ch0 * 8;
    const ushort* aSrc1 = Ag + (m0 + r1) * (long)lda + ch1 * 8;
    const ushort* bSrc  = Bg + (n0 + r0) * (long)K   + ch0 * 8;
    const int ldsOff = wave << 6;

    f32x16 acc[2];
    acc[0] = (f32x16)(0.0f);
    acc[1] = (f32x16)(0.0f);

#define ISSUE_STAGE4(buf, kt)                                                  \
    {                                                                          \
        gld_lds16(aSrc0 + (kt), &As[buf][ldsOff]);                             \
        gld_lds16(aSrc1 + (kt), &As[buf][256 + ldsOff]);                       \
        gld_lds16(bSrc  + (kt), &Bs[buf][ldsOff]);                             \
    }

    ISSUE_STAGE4(0, 0);
    int cur = 0;
    for (int kt = 0; kt < K; kt += 32) {
        __syncthreads();
        if (kt + 32 < K) ISSUE_STAGE4(cur ^ 1, kt + 32);

        bf16x8 af[2][2], bfr[2];
#pragma unroll
        for (int ks = 0; ks < 2; ++ks) {
            int c = ks * 2 + blk;
#pragma unroll
            for (int mi = 0; mi < 2; ++mi) {
                int r = wr * 64 + mi * 32 + ln31;
                af[ks][mi] = __builtin_bit_cast(bf16x8, As[cur][r * 4 + (c ^ swz(r))]);
            }
            int n = wc * 32 + ln31;
            bfr[ks] = __builtin_bit_cast(bf16x8, Bs[cur][n * 4 + (c ^ swz(n))]);
        }
#pragma unroll
        for (int ks = 0; ks < 2; ++ks)
#pragma unroll
            for (int mi = 0; mi < 2; ++mi)
                acc[mi] = __builtin_amdgcn_mfma_f32_32x32x16_bf16(
                    af[ks][mi], bfr[ks], acc[mi], 0, 0, 0);
        cur ^= 1;
    }
#undef ISSUE_STAGE4

    long col = n0 + wc * 32 + ln31;
    if (col < Nout) {
        float bs = bias ? bias[col] : 0.0f;
#pragma unroll
        for (int mi = 0; mi < 2; ++mi) {
#pragma unroll
            for (int reg = 0; reg < 16; ++reg) {
                long r2 = m0 + wr * 64 + mi * 32 + (reg & 3) + 8 * (reg >> 2) + 4 * blk;
                float v = acc[mi][reg] + bs;
                if (ACT == 1) {
                    v = fmaxf(v, 0.0f);
                    Cb[r2 * (long)ldC + col] = __float2bfloat16(v);
                } else if (ACT == 2) {
                    v = 1.0f / (1.0f + __expf(-v));
                    Cf[r2 * (long)ldC + col] = v;
                } else {
                    Cf[r2 * (long)ldC + col] = v;
                }
            }
        }
    }
}

template <int ACT>
__global__ __launch_bounds__(512, 8) void gemm8(
    const __hip_bfloat16* __restrict__ A, const __hip_bfloat16* __restrict__ Bt,
    const float* __restrict__ bias,
    float* __restrict__ Cf, __hip_bfloat16* __restrict__ Cb,
    int lda, int Nout, int ldC, int K)
{
    __shared__ uint4 As[2][512];
    __shared__ uint4 Bs[2][512];
    int bx = blockIdx.x, by = blockIdx.y;
    xcd_remap(bx, by);
    gemm_body8<ACT>((const ushort*)A, (const ushort*)Bt, bias, Cf, Cb,
                    lda, Nout, ldC, K,
                    (long)by * 128, (long)bx * 128, As, Bs);
}

template <int ACT>
__global__ __launch_bounds__(256, 8) void gemm4(
    const __hip_bfloat16* __restrict__ A, const __hip_bfloat16* __restrict__ Bt,
    const float* __restrict__ bias,
    float* __restrict__ Cf, __hip_bfloat16* __restrict__ Cb,
    int lda, int Nout, int ldC, int K)
{
    __shared__ uint4 As[2][512];
    __shared__ uint4 Bs[2][256];
    int bx = blockIdx.x, by = blockIdx.y;
    xcd_remap(bx, by);
    gemm_body4<ACT>((const ushort*)A, (const ushort*)Bt, bias, Cf, Cb,
                    lda, Nout, ldC, K,
                    (long)by * 128, (long)bx * 64, As, Bs);
}

// Fused: bx<16 -> p2 GEMM tiles (relu bf16), bx==16 -> sel-L2 (sigmoid f32).
__global__ __launch_bounds__(256, 8) void gemm4_fused23(
    const __hip_bfloat16* __restrict__ act1,   // B x 2048 (sel | policy)
    const __hip_bfloat16* __restrict__ p2t, const float* __restrict__ pb2,
    __hip_bfloat16* __restrict__ actB,
    const __hip_bfloat16* __restrict__ w2t, const float* __restrict__ sel_b2,
    float* __restrict__ outP)
{
    __shared__ uint4 As[2][512];
    __shared__ uint4 Bs[2][256];
    int bx = blockIdx.x, by = blockIdx.y;
    xcd_remap(bx, by);
    long m0 = (long)by * 128;
    if (bx < 16) {
        gemm_body4<1>((const ushort*)(act1 + 1024), (const ushort*)p2t, pb2,
                      nullptr, actB, 2048, 1024, 1024, 1024,
                      m0, (long)bx * 64, As, Bs);
    } else {
        gemm_body4<2>((const ushort*)act1, (const ushort*)w2t, sel_b2,
                      outP, nullptr, 2048, 64, 64, 1024,
                      m0, 0, As, Bs);
    }
}

// ---------------------------------------------------------------------------
// Prep: batched transpose-cast (6 weights) + rmean + bias concat + x-cast
// ---------------------------------------------------------------------------
struct PrepArgs {
    const float* src[6];
    __hip_bfloat16* dst[6];
    int Nsrc[6];
    int Npad[6];
    const float* ranges; float* rmean;
    const float* b1; const float* b2; float* bcat;
    const float* x; __hip_bfloat16* xbf;
};

__global__ void prep_kernel(PrepArgs a)
{
    int z = blockIdx.z;
    int tx = threadIdx.x, ty = threadIdx.y;   // 32 x 8
    int t = ty * 32 + tx;
    if (z == 7) {
        int bid = blockIdx.y * 32 + blockIdx.x;   // 0..1023
        const float4* s4 = (const float4*)a.x;
        for (int i = bid * 256 + t; i < B_DIM * D_DIM / 4; i += 1024 * 256) {
            float4 v = s4[i];
            __hip_bfloat16* d = a.xbf + (size_t)i * 4;
            d[0] = __float2bfloat16(v.x);
            d[1] = __float2bfloat16(v.y);
            d[2] = __float2bfloat16(v.z);
            d[3] = __float2bfloat16(v.w);
        }
        return;
    }
    if (z == 6) {
        if (blockIdx.x || blockIdx.y) return;
        for (int j = t; j < NUM * C_DIM; j += 256) {
            float s = 0.0f;
#pragma unroll
            for (int k = 0; k < K_RANGES; ++k) s += a.ranges[j * K_RANGES + k];
            a.rmean[j] = s * (1.0f / K_RANGES);
        }
        for (int j = t; j < 1024; j += 256) {
            a.bcat[j]        = a.b1[j];
            a.bcat[1024 + j] = a.b2[j];
        }
        return;
    }
    const int Nsrc = a.Nsrc[z], Npad = a.Npad[z];
    int n0 = blockIdx.x * 32, k0 = blockIdx.y * 32;
    if (n0 >= Npad) return;
    const float* src = a.src[z];
    __hip_bfloat16* dst = a.dst[z];
    __shared__ float tile[32][33];
#pragma unroll
    for (int i = 0; i < 32; i += 8) {
        int k = k0 + ty + i, n = n0 + tx;
        tile[ty + i][tx] = (n < Nsrc) ? src[(size_t)k * Nsrc + n] : 0.0f;
    }
    __syncthreads();
#pragma unroll
    for (int i = 0; i < 32; i += 8) {
        int n = n0 + ty + i, k = k0 + tx;
        dst[(size_t)n * D_DIM + k] = __float2bfloat16(tile[tx][ty + i]);
    }
}

// ---------------------------------------------------------------------------
// Finalize: one thread per (b, n)
// ---------------------------------------------------------------------------
__global__ void finalize_kernel(
    const float* __restrict__ x, const float* __restrict__ truth,
    const float* __restrict__ ua, const float* __restrict__ ub,
    const float* __restrict__ gum, const float* __restrict__ rmean,
    const float* __restrict__ P, const float* __restrict__ W,
    float* __restrict__ out_truth, float* __restrict__ out_xcf)
{
    int idx = blockIdx.x * 256 + threadIdx.x;
    if (idx >= B_DIM * N_DIM) return;
    int b = idx >> 6, n = idx & 63;

    float tx = truth[idx];
    out_truth[idx] = tx;

    float p  = P[idx];
    float ea = -1.0f / logf(ua[idx]);
    float eb = -1.0f / logf(ub[idx]);
    float no = p * ea;
    float probs = no / (no + (1.0f - p) * eb);

    const float* Wrow = W + (size_t)idx * 16;
    const float* grow = gum + (size_t)idx * 16;
    float lo[16], g[16], xv[16];
#pragma unroll
    for (int c = 0; c < 16; c += 4) {
        float4 v = *(const float4*)(Wrow + c);
        lo[c] = v.x; lo[c + 1] = v.y; lo[c + 2] = v.z; lo[c + 3] = v.w;
        float4 gv = *(const float4*)(grow + c);
        g[c] = gv.x; g[c + 1] = gv.y; g[c + 2] = gv.z; g[c + 3] = gv.w;
    }

    bool needx = (n < NCAUSAL) || (n >= NUM);
    if (needx) {
        const float* xrow = x + (size_t)idx * 16;
#pragma unroll
        for (int c = 0; c < 16; c += 4) {
            float4 v = *(const float4*)(xrow + c);
            xv[c] = v.x; xv[c + 1] = v.y; xv[c + 2] = v.z; xv[c + 3] = v.w;
        }
    }

    if (n < NCAUSAL) {
        int curr = 0; float best = xv[0];
#pragma unroll
        for (int c = 1; c < 16; ++c)
            if (xv[c] > best) { best = xv[c]; curr = c; }
#pragma unroll
        for (int c = 0; c < 16; ++c) lo[c] += (c < curr) ? -100.0f : 1.0f;
    }

    float mx = lo[0];
#pragma unroll
    for (int c = 1; c < 16; ++c) mx = fmaxf(mx, lo[c]);
    float s = 0.0f, pr[16];
#pragma unroll
    for (int c = 0; c < 16; ++c) { pr[c] = __expf(lo[c] - mx); s += pr[c]; }
    float inv = 1.0f / s;
#pragma unroll
    for (int c = 0; c < 16; ++c)
        pr[c] = (1.0f - SMOOTH) * pr[c] * inv + (SMOOTH / C_DIM);

    float t[16];
    float mx2 = -1e30f;
#pragma unroll
    for (int c = 0; c < 16; ++c) {
        t[c] = (__logf(pr[c]) + g[c]) * (1.0f / TAU);
        mx2 = fmaxf(mx2, t[c]);
    }
    float s2 = 0.0f;
#pragma unroll
    for (int c = 0; c < 16; ++c) { t[c] = __expf(t[c] - mx2); s2 += t[c]; }
    float inv2 = 1.0f / s2;

    if (n < NUM) {
        float xt = 0.0f;
#pragma unroll
        for (int c = 0; c < 16; ++c) xt += t[c] * inv2 * rmean[n * 16 + c];
        out_xcf[(size_t)b * 544 + n] = probs * xt + (1.0f - probs) * tx;
    } else {
        float* o = out_xcf + (size_t)b * 544 + 32 + (size_t)(n - NUM) * 16;
#pragma unroll
        for (int c = 0; c < 16; ++c)
            o[c] = probs * t[c] * inv2 + (1.0f - probs) * xv[c];
    }
}

// ---------------------------------------------------------------------------
extern "C" void kernel_launch(void* const* d_in, const int* in_sizes, int n_in,
                              void* d_out, int out_size, void* d_ws, size_t ws_size,
                              hipStream_t stream)
{
    const float* x      = (const float*)d_in[0];
    const float* truth  = (const float*)d_in[1];
    const float* sel_w1 = (const float*)d_in[2];
    const float* sel_b1 = (const float*)d_in[3];
    const float* sel_w2 = (const float*)d_in[4];
    const float* sel_b2 = (const float*)d_in[5];
    const float* pw1    = (const float*)d_in[6];
    const float* pb1    = (const float*)d_in[7];
    const float* pw2    = (const float*)d_in[8];
    const float* pb2    = (const float*)d_in[9];
    const float* pw3    = (const float*)d_in[10];
    const float* pb3    = (const float*)d_in[11];
    const float* pw4    = (const float*)d_in[12];
    const float* pb4    = (const float*)d_in[13];
    const float* ranges = (const float*)d_in[14];
    const float* ua     = (const float*)d_in[15];
    const float* ub     = (const float*)d_in[16];
    const float* gum    = (const float*)d_in[17];

    float* out       = (float*)d_out;
    float* out_truth = out;                       // B*N
    float* out_xcf   = out + 524288;              // B*544
    float* out_P     = out + 4980736;             // B*N
    float* out_W     = out + 5505024;             // B*D

    // workspace layout (16B-aligned sections)
    char* w = (char*)d_ws;
    size_t off = 0;
    __hip_bfloat16* A0   = (__hip_bfloat16*)(w + off); off += (size_t)B_DIM * D_DIM * 2;
    __hip_bfloat16* act1 = (__hip_bfloat16*)(w + off); off += (size_t)B_DIM * 2048 * 2;
    __hip_bfloat16* actB = (__hip_bfloat16*)(w + off); off += (size_t)B_DIM * HP * 2;
    __hip_bfloat16* actC = (__hip_bfloat16*)(w + off); off += (size_t)B_DIM * HP * 2;
    __hip_bfloat16* Wcat = (__hip_bfloat16*)(w + off); off += (size_t)2048 * D_DIM * 2;
    __hip_bfloat16* w2t  = (__hip_bfloat16*)(w + off); off += (size_t)128 * HS * 2;
    __hip_bfloat16* p2t  = (__hip_bfloat16*)(w + off); off += (size_t)HP * HP * 2;
    __hip_bfloat16* p3t  = (__hip_bfloat16*)(w + off); off += (size_t)HP * HP * 2;
    __hip_bfloat16* p4t  = (__hip_bfloat16*)(w + off); off += (size_t)D_DIM * HP * 2;
    float* rmean         = (float*)(w + off);          off += 512 * 4;
    float* bcat          = (float*)(w + off);          off += 2048 * 4;
    if (ws_size < off) return;

    PrepArgs pa;
    pa.src[0] = sel_w1; pa.dst[0] = Wcat;               pa.Nsrc[0] = HS;    pa.Npad[0] = 1024;
    pa.src[1] = pw1;    pa.dst[1] = Wcat + 1024 * 1024; pa.Nsrc[1] = HP;    pa.Npad[1] = 1024;
    pa.src[2] = sel_w2; pa.dst[2] = w2t;                pa.Nsrc[2] = N_DIM; pa.Npad[2] = 128;
    pa.src[3] = pw2;    pa.dst[3] = p2t;                pa.Nsrc[3] = HP;    pa.Npad[3] = 1024;
    pa.src[4] = pw3;    pa.dst[4] = p3t;                pa.Nsrc[4] = HP;    pa.Npad[4] = 1024;
    pa.src[5] = pw4;    pa.dst[5] = p4t;                pa.Nsrc[5] = D_DIM; pa.Npad[5] = 1024;
    pa.ranges = ranges; pa.rmean = rmean;
    pa.b1 = sel_b1; pa.b2 = pb1; pa.bcat = bcat;
    pa.x = x; pa.xbf = A0;

    prep_kernel<<<dim3(32, 32, 8), dim3(32, 8), 0, stream>>>(pa);

    // Layer 1 fused (sel + policy): A0 x Wcat^T -> act1 (B x 2048), relu
    // 1024 blocks, (512,8): target 4 blocks x 8 waves = 32 waves/CU
    gemm8<1><<<dim3(16, 64), 512, 0, stream>>>(A0, Wcat, bcat, nullptr, act1,
                                               D_DIM, 2048, 2048, D_DIM);
    // p2 GEMM (128x64 tiles, 1024 blocks) + sel layer-2 (64 blocks) fused
    gemm4_fused23<<<dim3(17, 64), 256, 0, stream>>>(act1, p2t, pb2, actB, w2t,
                                                    sel_b2, out_P);
    // p3 — 1024 blocks
    gemm4<1><<<dim3(16, 64), 256, 0, stream>>>(actB, p3t, pb3, nullptr, actC,
                                               HP, HP, HP, HP);
    // p4 -> W — 1024 blocks
    gemm4<0><<<dim3(16, 64), 256, 0, stream>>>(actC, p4t, pb4, out_W, nullptr,
                                               HP, D_DIM, D_DIM, HP);

    finalize_kernel<<<(B_DIM * N_DIM + 255) / 256, 256, 0, stream>>>(
        x, truth, ua, ub, gum, rmean, out_P, out_W, out_truth, out_xcf);
}

// Round 6
// 309.298 us; speedup vs baseline: 1.0174x; 1.0174x over previous
//
#include <hip/hip_runtime.h>
#include <hip/hip_bf16.h>
#include <cstdint>

#define B_DIM 8192
#define N_DIM 64
#define C_DIM 16
#define D_DIM 1024
#define NUM 32
#define NCAUSAL 16
#define K_RANGES 8
#define HS 1024
#define HP 1024
#define TAU 0.7f
#define SMOOTH 0.1f

typedef __bf16 bf16x8 __attribute__((ext_vector_type(8)));
typedef float f32x16 __attribute__((ext_vector_type(16)));

typedef const __attribute__((address_space(1))) uint32_t* gas_ptr;
typedef __attribute__((address_space(3))) uint32_t* las_ptr;

__device__ __forceinline__ void gld_lds16(const void* g, void* l) {
    __builtin_amdgcn_global_load_lds((gas_ptr)(uintptr_t)g,
                                     (las_ptr)(uint32_t)(uintptr_t)l,
                                     16, 0, 0);
}

__device__ __forceinline__ int swz(int r) { return (r & 3) ^ ((r >> 2) & 3); }

// bijective XCD swizzle (all grids here have nwg % 8 == 0)
__device__ __forceinline__ void xcd_remap(int& bx, int& by)
{
    int gx  = gridDim.x;
    int nwg = gx * gridDim.y;
    int lin = by * gx + bx;
    int cpx = nwg >> 3;
    int sw  = (lin & 7) * cpx + (lin >> 3);
    by = sw / gx;
    bx = sw - by * gx;
}

// ---------------------------------------------------------------------------
// K-split 8-wave 128x128 GEMM. Waves = (wr,wc,kg) 2x2x2; wave tile 64x64;
// wave kg accumulates K-half kg of each BK=64 step (two proven BK=32
// sub-stages per buffer -> byte-identical LDS swizzle/read pattern to the
// R3 0-conflict layout). r = 8 ds_read_b128 / 8 MFMA = 1.0 (was 1.5) and
// half the barriers. LDS 64KB dbuf -> 2 blocks x 8 waves = 16 waves/CU at
// every grid here (512-1024 blocks). Epilogue: kg=1 spills acc to LDS
// (swizzled, <=2-way), kg=0 adds + writes C. f32 add-order change is
// ~1e-7 scale vs the 0.0156 bf16 floor.
// lds layout (uint4): A = buf*1024 + half*512 + row*4 + ch ; B = 2048 + same
// ACT: 0 = none (f32 out), 1 = relu (bf16 out), 2 = sigmoid (f32 out)
// ---------------------------------------------------------------------------
template <int ACT>
__device__ __forceinline__ void gemm_ks_body(
    const ushort* __restrict__ Ag, const ushort* __restrict__ Bg,
    const float* __restrict__ bias,
    float* __restrict__ Cf, __hip_bfloat16* __restrict__ Cb,
    int lda, int Nout, int ldC, int K, long m0, long n0,
    uint4* lds)
{
    const int tid  = threadIdx.x;
    const int wave = tid >> 6;
    const int lane = tid & 63;
    const int ln31 = tid & 31, blk = (tid >> 5) & 1;
    const int wr = (wave >> 1) & 1, wc = wave & 1, kg = wave >> 2;

    const int row = tid >> 2;
    const int ch  = (tid & 3) ^ swz(row);
    const ushort* aSrc = Ag + (m0 + row) * (long)lda + ch * 8;
    const ushort* bSrc = Bg + (n0 + row) * (long)K   + ch * 8;
    const int ldsOff = wave << 6;   // wave-uniform dest base within a region

    f32x16 acc[2][2];
#pragma unroll
    for (int i = 0; i < 2; ++i)
#pragma unroll
        for (int j = 0; j < 2; ++j) acc[i][j] = (f32x16)(0.0f);

#define STG(buf, kt)                                                           \
    {                                                                          \
        gld_lds16(aSrc + (kt),      &lds[(buf) * 1024 + ldsOff]);              \
        gld_lds16(aSrc + (kt) + 32, &lds[(buf) * 1024 + 512 + ldsOff]);        \
        gld_lds16(bSrc + (kt),      &lds[2048 + (buf) * 1024 + ldsOff]);       \
        gld_lds16(bSrc + (kt) + 32, &lds[2048 + (buf) * 1024 + 512 + ldsOff]); \
    }

    STG(0, 0);
    int cur = 0;
    for (int kt = 0; kt < K; kt += 64) {
        __syncthreads();   // drains DMA for buf 'cur'; prev buf reads done
        if (kt + 64 < K) STG(cur ^ 1, kt + 64);

        const uint4* Ar = lds + cur * 1024 + kg * 512;
        const uint4* Br = lds + 2048 + cur * 1024 + kg * 512;

        bf16x8 af[2][2], bfr[2][2];
#pragma unroll
        for (int ks = 0; ks < 2; ++ks) {
            int c = ks * 2 + blk;
#pragma unroll
            for (int mi = 0; mi < 2; ++mi) {
                int r = wr * 64 + mi * 32 + ln31;
                af[ks][mi] = __builtin_bit_cast(bf16x8, Ar[r * 4 + (c ^ swz(r))]);
            }
#pragma unroll
            for (int ni = 0; ni < 2; ++ni) {
                int n = wc * 64 + ni * 32 + ln31;
                bfr[ks][ni] = __builtin_bit_cast(bf16x8, Br[n * 4 + (c ^ swz(n))]);
            }
        }
#pragma unroll
        for (int ks = 0; ks < 2; ++ks)
#pragma unroll
            for (int mi = 0; mi < 2; ++mi)
#pragma unroll
                for (int ni = 0; ni < 2; ++ni)
                    acc[mi][ni] = __builtin_amdgcn_mfma_f32_32x32x16_bf16(
                        af[ks][mi], bfr[ks][ni], acc[mi][ni], 0, 0, 0);
        cur ^= 1;
    }
#undef STG

    // ---- cross-wave K-half merge (LDS reused; swizzled, <=2-way/phase) ----
    __syncthreads();   // all LDS reads of the K-loop are complete
    const int rbase = (wr * 2 + wc) * 1024;   // 16 KB region per (wr,wc)
    if (kg == 1) {
#pragma unroll
        for (int mi = 0; mi < 2; ++mi)
#pragma unroll
            for (int ni = 0; ni < 2; ++ni)
#pragma unroll
                for (int q = 0; q < 4; ++q) {
                    float4 t = { acc[mi][ni][q * 4 + 0], acc[mi][ni][q * 4 + 1],
                                 acc[mi][ni][q * 4 + 2], acc[mi][ni][q * 4 + 3] };
                    int i = mi * 8 + ni * 4 + q;
                    lds[rbase + lane * 16 + (i ^ (lane & 7))] =
                        __builtin_bit_cast(uint4, t);
                }
    }
    __syncthreads();
    if (kg == 0) {
#pragma unroll
        for (int mi = 0; mi < 2; ++mi)
#pragma unroll
            for (int ni = 0; ni < 2; ++ni)
#pragma unroll
                for (int q = 0; q < 4; ++q) {
                    int i = mi * 8 + ni * 4 + q;
                    float4 t = __builtin_bit_cast(
                        float4, lds[rbase + lane * 16 + (i ^ (lane & 7))]);
                    acc[mi][ni][q * 4 + 0] += t.x;
                    acc[mi][ni][q * 4 + 1] += t.y;
                    acc[mi][ni][q * 4 + 2] += t.z;
                    acc[mi][ni][q * 4 + 3] += t.w;
                }

        // epilogue — proven 32x32 C/D mapping (kg=0 waves cover 128x128)
#pragma unroll
        for (int ni = 0; ni < 2; ++ni) {
            long col = n0 + wc * 64 + ni * 32 + ln31;
            if (col >= Nout) continue;
            float bs = bias ? bias[col] : 0.0f;
#pragma unroll
            for (int mi = 0; mi < 2; ++mi) {
#pragma unroll
                for (int reg = 0; reg < 16; ++reg) {
                    long r2 = m0 + wr * 64 + mi * 32 + (reg & 3) + 8 * (reg >> 2) + 4 * blk;
                    float v = acc[mi][ni][reg] + bs;
                    if (ACT == 1) {
                        v = fmaxf(v, 0.0f);
                        Cb[r2 * (long)ldC + col] = __float2bfloat16(v);
                    } else if (ACT == 2) {
                        v = 1.0f / (1.0f + __expf(-v));
                        Cf[r2 * (long)ldC + col] = v;
                    } else {
                        Cf[r2 * (long)ldC + col] = v;
                    }
                }
            }
        }
    }
}

template <int ACT>
__global__ __launch_bounds__(512, 4) void gemm_ks(
    const __hip_bfloat16* __restrict__ A, const __hip_bfloat16* __restrict__ Bt,
    const float* __restrict__ bias,
    float* __restrict__ Cf, __hip_bfloat16* __restrict__ Cb,
    int lda, int Nout, int ldC, int K)
{
    __shared__ uint4 lds[4096];   // 64 KB
    int bx = blockIdx.x, by = blockIdx.y;
    xcd_remap(bx, by);
    gemm_ks_body<ACT>((const ushort*)A, (const ushort*)Bt, bias, Cf, Cb,
                      lda, Nout, ldC, K,
                      (long)by * 128, (long)bx * 128, lds);
}

// Fused: bx<8 -> p2 GEMM (relu bf16), bx==8 -> sel-L2 (sigmoid f32).
__global__ __launch_bounds__(512, 4) void gemm_ks_fused23(
    const __hip_bfloat16* __restrict__ act1,   // B x 2048 (sel | policy)
    const __hip_bfloat16* __restrict__ p2t, const float* __restrict__ pb2,
    __hip_bfloat16* __restrict__ actB,
    const __hip_bfloat16* __restrict__ w2t, const float* __restrict__ sel_b2,
    float* __restrict__ outP)
{
    __shared__ uint4 lds[4096];
    int bx = blockIdx.x, by = blockIdx.y;
    xcd_remap(bx, by);
    long m0 = (long)by * 128;
    if (bx < 8) {
        gemm_ks_body<1>((const ushort*)(act1 + 1024), (const ushort*)p2t, pb2,
                        nullptr, actB, 2048, 1024, 1024, 1024,
                        m0, (long)bx * 128, lds);
    } else {
        gemm_ks_body<2>((const ushort*)act1, (const ushort*)w2t, sel_b2,
                        outP, nullptr, 2048, 64, 64, 1024,
                        m0, 0, lds);
    }
}

// ---------------------------------------------------------------------------
// Prep: batched transpose-cast (6 weights) + rmean + bias concat + x-cast
// ---------------------------------------------------------------------------
struct PrepArgs {
    const float* src[6];
    __hip_bfloat16* dst[6];
    int Nsrc[6];
    int Npad[6];
    const float* ranges; float* rmean;
    const float* b1; const float* b2; float* bcat;
    const float* x; __hip_bfloat16* xbf;
};

__global__ void prep_kernel(PrepArgs a)
{
    int z = blockIdx.z;
    int tx = threadIdx.x, ty = threadIdx.y;   // 32 x 8
    int t = ty * 32 + tx;
    if (z == 7) {
        int bid = blockIdx.y * 32 + blockIdx.x;   // 0..1023
        const float4* s4 = (const float4*)a.x;
        for (int i = bid * 256 + t; i < B_DIM * D_DIM / 4; i += 1024 * 256) {
            float4 v = s4[i];
            __hip_bfloat16* d = a.xbf + (size_t)i * 4;
            d[0] = __float2bfloat16(v.x);
            d[1] = __float2bfloat16(v.y);
            d[2] = __float2bfloat16(v.z);
            d[3] = __float2bfloat16(v.w);
        }
        return;
    }
    if (z == 6) {
        if (blockIdx.x || blockIdx.y) return;
        for (int j = t; j < NUM * C_DIM; j += 256) {
            float s = 0.0f;
#pragma unroll
            for (int k = 0; k < K_RANGES; ++k) s += a.ranges[j * K_RANGES + k];
            a.rmean[j] = s * (1.0f / K_RANGES);
        }
        for (int j = t; j < 1024; j += 256) {
            a.bcat[j]        = a.b1[j];
            a.bcat[1024 + j] = a.b2[j];
        }
        return;
    }
    const int Nsrc = a.Nsrc[z], Npad = a.Npad[z];
    int n0 = blockIdx.x * 32, k0 = blockIdx.y * 32;
    if (n0 >= Npad) return;
    const float* src = a.src[z];
    __hip_bfloat16* dst = a.dst[z];
    __shared__ float tile[32][33];
#pragma unroll
    for (int i = 0; i < 32; i += 8) {
        int k = k0 + ty + i, n = n0 + tx;
        tile[ty + i][tx] = (n < Nsrc) ? src[(size_t)k * Nsrc + n] : 0.0f;
    }
    __syncthreads();
#pragma unroll
    for (int i = 0; i < 32; i += 8) {
        int n = n0 + ty + i, k = k0 + tx;
        dst[(size_t)n * D_DIM + k] = __float2bfloat16(tile[tx][ty + i]);
    }
}

// ---------------------------------------------------------------------------
// Finalize: one thread per (b, n)
// ---------------------------------------------------------------------------
__global__ void finalize_kernel(
    const float* __restrict__ x, const float* __restrict__ truth,
    const float* __restrict__ ua, const float* __restrict__ ub,
    const float* __restrict__ gum, const float* __restrict__ rmean,
    const float* __restrict__ P, const float* __restrict__ W,
    float* __restrict__ out_truth, float* __restrict__ out_xcf)
{
    int idx = blockIdx.x * 256 + threadIdx.x;
    if (idx >= B_DIM * N_DIM) return;
    int b = idx >> 6, n = idx & 63;

    float tx = truth[idx];
    out_truth[idx] = tx;

    float p  = P[idx];
    float ea = -1.0f / logf(ua[idx]);
    float eb = -1.0f / logf(ub[idx]);
    float no = p * ea;
    float probs = no / (no + (1.0f - p) * eb);

    const float* Wrow = W + (size_t)idx * 16;
    const float* grow = gum + (size_t)idx * 16;
    float lo[16], g[16], xv[16];
#pragma unroll
    for (int c = 0; c < 16; c += 4) {
        float4 v = *(const float4*)(Wrow + c);
        lo[c] = v.x; lo[c + 1] = v.y; lo[c + 2] = v.z; lo[c + 3] = v.w;
        float4 gv = *(const float4*)(grow + c);
        g[c] = gv.x; g[c + 1] = gv.y; g[c + 2] = gv.z; g[c + 3] = gv.w;
    }

    bool needx = (n < NCAUSAL) || (n >= NUM);
    if (needx) {
        const float* xrow = x + (size_t)idx * 16;
#pragma unroll
        for (int c = 0; c < 16; c += 4) {
            float4 v = *(const float4*)(xrow + c);
            xv[c] = v.x; xv[c + 1] = v.y; xv[c + 2] = v.z; xv[c + 3] = v.w;
        }
    }

    if (n < NCAUSAL) {
        int curr = 0; float best = xv[0];
#pragma unroll
        for (int c = 1; c < 16; ++c)
            if (xv[c] > best) { best = xv[c]; curr = c; }
#pragma unroll
        for (int c = 0; c < 16; ++c) lo[c] += (c < curr) ? -100.0f : 1.0f;
    }

    float mx = lo[0];
#pragma unroll
    for (int c = 1; c < 16; ++c) mx = fmaxf(mx, lo[c]);
    float s = 0.0f, pr[16];
#pragma unroll
    for (int c = 0; c < 16; ++c) { pr[c] = __expf(lo[c] - mx); s += pr[c]; }
    float inv = 1.0f / s;
#pragma unroll
    for (int c = 0; c < 16; ++c)
        pr[c] = (1.0f - SMOOTH) * pr[c] * inv + (SMOOTH / C_DIM);

    float t[16];
    float mx2 = -1e30f;
#pragma unroll
    for (int c = 0; c < 16; ++c) {
        t[c] = (__logf(pr[c]) + g[c]) * (1.0f / TAU);
        mx2 = fmaxf(mx2, t[c]);
    }
    float s2 = 0.0f;
#pragma unroll
    for (int c = 0; c < 16; ++c) { t[c] = __expf(t[c] - mx2); s2 += t[c]; }
    float inv2 = 1.0f / s2;

    if (n < NUM) {
        float xt = 0.0f;
#pragma unroll
        for (int c = 0; c < 16; ++c) xt += t[c] * inv2 * rmean[n * 16 + c];
        out_xcf[(size_t)b * 544 + n] = probs * xt + (1.0f - probs) * tx;
    } else {
        float* o = out_xcf + (size_t)b * 544 + 32 + (size_t)(n - NUM) * 16;
#pragma unroll
        for (int c = 0; c < 16; ++c)
            o[c] = probs * t[c] * inv2 + (1.0f - probs) * xv[c];
    }
}

// ---------------------------------------------------------------------------
extern "C" void kernel_launch(void* const* d_in, const int* in_sizes, int n_in,
                              void* d_out, int out_size, void* d_ws, size_t ws_size,
                              hipStream_t stream)
{
    const float* x      = (const float*)d_in[0];
    const float* truth  = (const float*)d_in[1];
    const float* sel_w1 = (const float*)d_in[2];
    const float* sel_b1 = (const float*)d_in[3];
    const float* sel_w2 = (const float*)d_in[4];
    const float* sel_b2 = (const float*)d_in[5];
    const float* pw1    = (const float*)d_in[6];
    const float* pb1    = (const float*)d_in[7];
    const float* pw2    = (const float*)d_in[8];
    const float* pb2    = (const float*)d_in[9];
    const float* pw3    = (const float*)d_in[10];
    const float* pb3    = (const float*)d_in[11];
    const float* pw4    = (const float*)d_in[12];
    const float* pb4    = (const float*)d_in[13];
    const float* ranges = (const float*)d_in[14];
    const float* ua     = (const float*)d_in[15];
    const float* ub     = (const float*)d_in[16];
    const float* gum    = (const float*)d_in[17];

    float* out       = (float*)d_out;
    float* out_truth = out;                       // B*N
    float* out_xcf   = out + 524288;              // B*544
    float* out_P     = out + 4980736;             // B*N
    float* out_W     = out + 5505024;             // B*D

    // workspace layout (16B-aligned sections)
    char* w = (char*)d_ws;
    size_t off = 0;
    __hip_bfloat16* A0   = (__hip_bfloat16*)(w + off); off += (size_t)B_DIM * D_DIM * 2;
    __hip_bfloat16* act1 = (__hip_bfloat16*)(w + off); off += (size_t)B_DIM * 2048 * 2;
    __hip_bfloat16* actB = (__hip_bfloat16*)(w + off); off += (size_t)B_DIM * HP * 2;
    __hip_bfloat16* actC = (__hip_bfloat16*)(w + off); off += (size_t)B_DIM * HP * 2;
    __hip_bfloat16* Wcat = (__hip_bfloat16*)(w + off); off += (size_t)2048 * D_DIM * 2;
    __hip_bfloat16* w2t  = (__hip_bfloat16*)(w + off); off += (size_t)128 * HS * 2;
    __hip_bfloat16* p2t  = (__hip_bfloat16*)(w + off); off += (size_t)HP * HP * 2;
    __hip_bfloat16* p3t  = (__hip_bfloat16*)(w + off); off += (size_t)HP * HP * 2;
    __hip_bfloat16* p4t  = (__hip_bfloat16*)(w + off); off += (size_t)D_DIM * HP * 2;
    float* rmean         = (float*)(w + off);          off += 512 * 4;
    float* bcat          = (float*)(w + off);          off += 2048 * 4;
    if (ws_size < off) return;

    PrepArgs pa;
    pa.src[0] = sel_w1; pa.dst[0] = Wcat;               pa.Nsrc[0] = HS;    pa.Npad[0] = 1024;
    pa.src[1] = pw1;    pa.dst[1] = Wcat + 1024 * 1024; pa.Nsrc[1] = HP;    pa.Npad[1] = 1024;
    pa.src[2] = sel_w2; pa.dst[2] = w2t;                pa.Nsrc[2] = N_DIM; pa.Npad[2] = 128;
    pa.src[3] = pw2;    pa.dst[3] = p2t;                pa.Nsrc[3] = HP;    pa.Npad[3] = 1024;
    pa.src[4] = pw3;    pa.dst[4] = p3t;                pa.Nsrc[4] = HP;    pa.Npad[4] = 1024;
    pa.src[5] = pw4;    pa.dst[5] = p4t;                pa.Nsrc[5] = D_DIM; pa.Npad[5] = 1024;
    pa.ranges = ranges; pa.rmean = rmean;
    pa.b1 = sel_b1; pa.b2 = pb1; pa.bcat = bcat;
    pa.x = x; pa.xbf = A0;

    prep_kernel<<<dim3(32, 32, 8), dim3(32, 8), 0, stream>>>(pa);

    // Layer 1 fused (sel + policy): A0 x Wcat^T -> act1 (B x 2048), relu
    gemm_ks<1><<<dim3(16, 64), 512, 0, stream>>>(A0, Wcat, bcat, nullptr, act1,
                                                 D_DIM, 2048, 2048, D_DIM);
    // p2 GEMM + sel layer-2 (fused launch) — 576 blocks
    gemm_ks_fused23<<<dim3(9, 64), 512, 0, stream>>>(act1, p2t, pb2, actB, w2t,
                                                     sel_b2, out_P);
    // p3 — 512 blocks
    gemm_ks<1><<<dim3(8, 64), 512, 0, stream>>>(actB, p3t, pb3, nullptr, actC,
                                                HP, HP, HP, HP);
    // p4 -> W — 512 blocks
    gemm_ks<0><<<dim3(8, 64), 512, 0, stream>>>(actC, p4t, pb4, out_W, nullptr,
                                                HP, D_DIM, D_DIM, HP);

    finalize_kernel<<<(B_DIM * N_DIM + 255) / 256, 256, 0, stream>>>(
        x, truth, ua, ub, gum, rmean, out_P, out_W, out_truth, out_xcf);
}

// Round 7
// 300.331 us; speedup vs baseline: 1.0478x; 1.0299x over previous
//
#include <hip/hip_runtime.h>
#include <hip/hip_bf16.h>
#include <cstdint>

#define B_DIM 8192
#define N_DIM 64
#define C_DIM 16
#define D_DIM 1024
#define NUM 32
#define NCAUSAL 16
#define K_RANGES 8
#define HS 1024
#define HP 1024
#define TAU 0.7f
#define SMOOTH 0.1f

typedef __bf16 bf16x8 __attribute__((ext_vector_type(8)));
typedef float f32x16 __attribute__((ext_vector_type(16)));

typedef const __attribute__((address_space(1))) uint32_t* gas_ptr;
typedef __attribute__((address_space(3))) uint32_t* las_ptr;

__device__ __forceinline__ void gld_lds16(const void* g, void* l) {
    __builtin_amdgcn_global_load_lds((gas_ptr)(uintptr_t)g,
                                     (las_ptr)(uint32_t)(uintptr_t)l,
                                     16, 0, 0);
}

__device__ __forceinline__ int swz(int r) { return (r & 3) ^ ((r >> 2) & 3); }

// bijective XCD swizzle (all grids here have nwg % 8 == 0)
__device__ __forceinline__ void xcd_remap(int& bx, int& by)
{
    int gx  = gridDim.x;
    int nwg = gx * gridDim.y;
    int lin = by * gx + bx;
    int cpx = nwg >> 3;
    int sw  = (lin & 7) * cpx + (lin >> 3);
    by = sw / gx;
    bx = sw - by * gx;
}

// ---------------------------------------------------------------------------
// 8-wave 128x128 GEMM body, counted-vmcnt 3-buffer pipeline — R4-proven
// (best total 293.7, absmax 0.015625). Bodies untouched this round.
// ACT: 0 = f32 out; 1 = relu bf16; 2 = sigmoid f32;
//      3 = f32 out + export acc to accExp (for the fused-finalize kernel)
// ---------------------------------------------------------------------------
template <int ACT>
__device__ __forceinline__ void gemm_body8(
    const ushort* __restrict__ Ag, const ushort* __restrict__ Bg,
    const float* __restrict__ bias,
    float* __restrict__ Cf, __hip_bfloat16* __restrict__ Cb,
    int lda, int Nout, int ldC, int K, long m0, long n0,
    uint4 (*As)[512], uint4 (*Bs)[512], f32x16* accExp = nullptr)
{
    const int tid  = threadIdx.x;
    const int wave = tid >> 6;
    const int ln31 = tid & 31, blk = (tid >> 5) & 1;
    const int wr = wave >> 2, wc = wave & 3;

    const int row = tid >> 2;
    const int ch  = (tid & 3) ^ swz(row);
    const ushort* aSrc = Ag + (m0 + row) * (long)lda + ch * 8;
    const ushort* bSrc = Bg + (n0 + row) * (long)K   + ch * 8;
    const int ldsOff = wave << 6;   // wave-uniform LDS base

    f32x16 acc[2];
    acc[0] = (f32x16)(0.0f);
    acc[1] = (f32x16)(0.0f);

#define ISSUE_STAGE8(buf, kt)                                                  \
    {                                                                          \
        gld_lds16(aSrc + (kt), &As[buf][ldsOff]);                              \
        gld_lds16(bSrc + (kt), &Bs[buf][ldsOff]);                              \
    }

    const int nt = K >> 5;
    ISSUE_STAGE8(0, 0);
    ISSUE_STAGE8(1, 32);

    int rb = 0;   // read buffer = t % 3
    for (int t = 0; t < nt; ++t) {
        if (t < nt - 1) {
            asm volatile("s_waitcnt vmcnt(2)" ::: "memory");
        } else {
            asm volatile("s_waitcnt vmcnt(0)" ::: "memory");
        }
        __builtin_amdgcn_s_barrier();

        if (t + 2 < nt) {
            int sb = rb + 2; if (sb >= 3) sb -= 3;
            ISSUE_STAGE8(sb, (t + 2) * 32);
        }

        bf16x8 af[2][2], bfr[2];
#pragma unroll
        for (int ks = 0; ks < 2; ++ks) {
            int c = ks * 2 + blk;
#pragma unroll
            for (int mi = 0; mi < 2; ++mi) {
                int r = wr * 64 + mi * 32 + ln31;
                af[ks][mi] = __builtin_bit_cast(bf16x8, As[rb][r * 4 + (c ^ swz(r))]);
            }
            int n = wc * 32 + ln31;
            bfr[ks] = __builtin_bit_cast(bf16x8, Bs[rb][n * 4 + (c ^ swz(n))]);
        }
#pragma unroll
        for (int ks = 0; ks < 2; ++ks)
#pragma unroll
            for (int mi = 0; mi < 2; ++mi)
                acc[mi] = __builtin_amdgcn_mfma_f32_32x32x16_bf16(
                    af[ks][mi], bfr[ks], acc[mi], 0, 0, 0);

        rb = (rb == 2) ? 0 : rb + 1;
    }
#undef ISSUE_STAGE8

    if (ACT == 3) { accExp[0] = acc[0]; accExp[1] = acc[1]; }

    long col = n0 + wc * 32 + ln31;
    if (col < Nout) {
        float bs = bias ? bias[col] : 0.0f;
#pragma unroll
        for (int mi = 0; mi < 2; ++mi) {
#pragma unroll
            for (int reg = 0; reg < 16; ++reg) {
                long r2 = m0 + wr * 64 + mi * 32 + (reg & 3) + 8 * (reg >> 2) + 4 * blk;
                float v = acc[mi][reg] + bs;
                if (ACT == 1) {
                    v = fmaxf(v, 0.0f);
                    Cb[r2 * (long)ldC + col] = __float2bfloat16(v);
                } else if (ACT == 2) {
                    v = 1.0f / (1.0f + __expf(-v));
                    Cf[r2 * (long)ldC + col] = v;
                } else {
                    Cf[r2 * (long)ldC + col] = v;
                }
            }
        }
    }
}

template <int ACT>
__global__ __launch_bounds__(512, 4) void gemm8(
    const __hip_bfloat16* __restrict__ A, const __hip_bfloat16* __restrict__ Bt,
    const float* __restrict__ bias,
    float* __restrict__ Cf, __hip_bfloat16* __restrict__ Cb,
    int lda, int Nout, int ldC, int K)
{
    __shared__ uint4 As[3][512];
    __shared__ uint4 Bs[3][512];
    int bx = blockIdx.x, by = blockIdx.y;
    xcd_remap(bx, by);
    gemm_body8<ACT>((const ushort*)A, (const ushort*)Bt, bias, Cf, Cb,
                    lda, Nout, ldC, K,
                    (long)by * 128, (long)bx * 128, As, Bs);
}

// Fused: bx<8 -> p2 GEMM (relu bf16), bx==8 -> sel-L2 (sigmoid f32).
__global__ __launch_bounds__(512, 4) void gemm8_fused23(
    const __hip_bfloat16* __restrict__ act1,   // B x 2048 (sel | policy)
    const __hip_bfloat16* __restrict__ p2t, const float* __restrict__ pb2,
    __hip_bfloat16* __restrict__ actB,
    const __hip_bfloat16* __restrict__ w2t, const float* __restrict__ sel_b2,
    float* __restrict__ outP)
{
    __shared__ uint4 As[3][512];
    __shared__ uint4 Bs[3][512];
    int bx = blockIdx.x, by = blockIdx.y;
    xcd_remap(bx, by);
    long m0 = (long)by * 128;
    if (bx < 8) {
        gemm_body8<1>((const ushort*)(act1 + 1024), (const ushort*)p2t, pb2,
                      nullptr, actB, 2048, 1024, 1024, 1024,
                      m0, (long)bx * 128, As, Bs);
    } else {
        gemm_body8<2>((const ushort*)act1, (const ushort*)w2t, sel_b2,
                      outP, nullptr, 2048, 64, 64, 1024,
                      m0, 0, As, Bs);
    }
}

// ---------------------------------------------------------------------------
// p4 + finalize fused. The block's 128x128 W tile covers exactly the (b,n)
// pairs b in [m0,m0+128), n in [n0/16, n0/16+8). W is stored to global via
// the proven path (bit-identical), then acc+bias is transposed through the
// staging LDS (reused; two 64-row halves of a padded 64x132 f32 tile) and
// the finalize math runs verbatim from LDS — eliminating the standalone
// finalize kernel and its 32MB W re-read. Outputs bit-identical.
// ---------------------------------------------------------------------------
struct FinArgs {
    const float* x; const float* truth; const float* ua; const float* ub;
    const float* gum; const float* rmean; const float* P;
    float* out_truth; float* out_xcf;
};

__global__ __launch_bounds__(512, 4) void gemm8_final(
    const __hip_bfloat16* __restrict__ A, const __hip_bfloat16* __restrict__ Bt,
    const float* __restrict__ bias, float* __restrict__ W,
    int lda, int K, FinArgs fa)
{
    __shared__ uint4 smem[3072];   // 48 KB: staging during loop, W tile after
    uint4 (*As)[512] = reinterpret_cast<uint4(*)[512]>(smem);
    uint4 (*Bs)[512] = reinterpret_cast<uint4(*)[512]>(smem + 1536);

    int bx = blockIdx.x, by = blockIdx.y;
    xcd_remap(bx, by);
    const long m0 = (long)by * 128;
    const long n0 = (long)bx * 128;

    f32x16 accE[2];
    gemm_body8<3>((const ushort*)A, (const ushort*)Bt, bias, W, nullptr,
                  lda, 1024, 1024, K, m0, n0, As, Bs, accE);

    // ---- fused finalize ----
    const int tid  = threadIdx.x;
    const int wave = tid >> 6;
    const int ln31 = tid & 31, blk = (tid >> 5) & 1;
    const int wr = wave >> 2, wc = wave & 3;

    float* tile = (float*)smem;               // 64 rows x 132 floats
    const float bs = bias[n0 + wc * 32 + ln31];

    const int lb = tid >> 3;                  // 0..63 (row in half)
    const int ng = tid & 7;                   // 0..7  (16-col group)
    const int n  = (int)(n0 >> 4) + ng;       // global n in 0..63

    for (int h = 0; h < 2; ++h) {
        __syncthreads();   // h=0: staging reads done; h=1: prev tile reads done
        if (wr == h) {
#pragma unroll
            for (int mi = 0; mi < 2; ++mi)
#pragma unroll
                for (int reg = 0; reg < 16; ++reg) {
                    int lr = mi * 32 + (reg & 3) + 8 * (reg >> 2) + 4 * blk;
                    tile[lr * 132 + wc * 32 + ln31] = accE[mi][reg] + bs;
                }
        }
        __syncthreads();

        long b   = m0 + h * 64 + lb;
        long idx = b * 64 + n;

        float tx = fa.truth[idx];
        fa.out_truth[idx] = tx;

        float p  = fa.P[idx];
        float ea = -1.0f / logf(fa.ua[idx]);
        float eb = -1.0f / logf(fa.ub[idx]);
        float no = p * ea;
        float probs = no / (no + (1.0f - p) * eb);

        const float* Wrow = tile + lb * 132 + ng * 16;
        const float* grow = fa.gum + (size_t)idx * 16;
        float lo[16], g[16], xv[16];
#pragma unroll
        for (int c = 0; c < 16; c += 4) {
            float4 v = *(const float4*)(Wrow + c);
            lo[c] = v.x; lo[c + 1] = v.y; lo[c + 2] = v.z; lo[c + 3] = v.w;
            float4 gv = *(const float4*)(grow + c);
            g[c] = gv.x; g[c + 1] = gv.y; g[c + 2] = gv.z; g[c + 3] = gv.w;
        }

        bool needx = (n < NCAUSAL) || (n >= NUM);
        if (needx) {
            const float* xrow = fa.x + (size_t)idx * 16;
#pragma unroll
            for (int c = 0; c < 16; c += 4) {
                float4 v = *(const float4*)(xrow + c);
                xv[c] = v.x; xv[c + 1] = v.y; xv[c + 2] = v.z; xv[c + 3] = v.w;
            }
        }

        if (n < NCAUSAL) {
            int curr = 0; float best = xv[0];
#pragma unroll
            for (int c = 1; c < 16; ++c)
                if (xv[c] > best) { best = xv[c]; curr = c; }
#pragma unroll
            for (int c = 0; c < 16; ++c) lo[c] += (c < curr) ? -100.0f : 1.0f;
        }

        float mx = lo[0];
#pragma unroll
        for (int c = 1; c < 16; ++c) mx = fmaxf(mx, lo[c]);
        float s = 0.0f, pr[16];
#pragma unroll
        for (int c = 0; c < 16; ++c) { pr[c] = __expf(lo[c] - mx); s += pr[c]; }
        float inv = 1.0f / s;
#pragma unroll
        for (int c = 0; c < 16; ++c)
            pr[c] = (1.0f - SMOOTH) * pr[c] * inv + (SMOOTH / C_DIM);

        float t[16];
        float mx2 = -1e30f;
#pragma unroll
        for (int c = 0; c < 16; ++c) {
            t[c] = (__logf(pr[c]) + g[c]) * (1.0f / TAU);
            mx2 = fmaxf(mx2, t[c]);
        }
        float s2 = 0.0f;
#pragma unroll
        for (int c = 0; c < 16; ++c) { t[c] = __expf(t[c] - mx2); s2 += t[c]; }
        float inv2 = 1.0f / s2;

        if (n < NUM) {
            float xt = 0.0f;
#pragma unroll
            for (int c = 0; c < 16; ++c) xt += t[c] * inv2 * fa.rmean[n * 16 + c];
            fa.out_xcf[(size_t)b * 544 + n] = probs * xt + (1.0f - probs) * tx;
        } else {
            float* o = fa.out_xcf + (size_t)b * 544 + 32 + (size_t)(n - NUM) * 16;
#pragma unroll
            for (int c = 0; c < 16; ++c)
                o[c] = probs * t[c] * inv2 + (1.0f - probs) * xv[c];
        }
    }
}

// ---------------------------------------------------------------------------
// Prep: batched transpose-cast (6 weights) + rmean + bias concat + x-cast
// ---------------------------------------------------------------------------
struct PrepArgs {
    const float* src[6];
    __hip_bfloat16* dst[6];
    int Nsrc[6];
    int Npad[6];
    const float* ranges; float* rmean;
    const float* b1; const float* b2; float* bcat;
    const float* x; __hip_bfloat16* xbf;
};

__global__ void prep_kernel(PrepArgs a)
{
    int z = blockIdx.z;
    int tx = threadIdx.x, ty = threadIdx.y;   // 32 x 8
    int t = ty * 32 + tx;
    if (z == 7) {
        int bid = blockIdx.y * 32 + blockIdx.x;   // 0..1023
        const float4* s4 = (const float4*)a.x;
        for (int i = bid * 256 + t; i < B_DIM * D_DIM / 4; i += 1024 * 256) {
            float4 v = s4[i];
            __hip_bfloat16* d = a.xbf + (size_t)i * 4;
            d[0] = __float2bfloat16(v.x);
            d[1] = __float2bfloat16(v.y);
            d[2] = __float2bfloat16(v.z);
            d[3] = __float2bfloat16(v.w);
        }
        return;
    }
    if (z == 6) {
        if (blockIdx.x || blockIdx.y) return;
        for (int j = t; j < NUM * C_DIM; j += 256) {
            float s = 0.0f;
#pragma unroll
            for (int k = 0; k < K_RANGES; ++k) s += a.ranges[j * K_RANGES + k];
            a.rmean[j] = s * (1.0f / K_RANGES);
        }
        for (int j = t; j < 1024; j += 256) {
            a.bcat[j]        = a.b1[j];
            a.bcat[1024 + j] = a.b2[j];
        }
        return;
    }
    const int Nsrc = a.Nsrc[z], Npad = a.Npad[z];
    int n0 = blockIdx.x * 32, k0 = blockIdx.y * 32;
    if (n0 >= Npad) return;
    const float* src = a.src[z];
    __hip_bfloat16* dst = a.dst[z];
    __shared__ float tile[32][33];
#pragma unroll
    for (int i = 0; i < 32; i += 8) {
        int k = k0 + ty + i, n = n0 + tx;
        tile[ty + i][tx] = (n < Nsrc) ? src[(size_t)k * Nsrc + n] : 0.0f;
    }
    __syncthreads();
#pragma unroll
    for (int i = 0; i < 32; i += 8) {
        int n = n0 + ty + i, k = k0 + tx;
        dst[(size_t)n * D_DIM + k] = __float2bfloat16(tile[tx][ty + i]);
    }
}

// ---------------------------------------------------------------------------
extern "C" void kernel_launch(void* const* d_in, const int* in_sizes, int n_in,
                              void* d_out, int out_size, void* d_ws, size_t ws_size,
                              hipStream_t stream)
{
    const float* x      = (const float*)d_in[0];
    const float* truth  = (const float*)d_in[1];
    const float* sel_w1 = (const float*)d_in[2];
    const float* sel_b1 = (const float*)d_in[3];
    const float* sel_w2 = (const float*)d_in[4];
    const float* sel_b2 = (const float*)d_in[5];
    const float* pw1    = (const float*)d_in[6];
    const float* pb1    = (const float*)d_in[7];
    const float* pw2    = (const float*)d_in[8];
    const float* pb2    = (const float*)d_in[9];
    const float* pw3    = (const float*)d_in[10];
    const float* pb3    = (const float*)d_in[11];
    const float* pw4    = (const float*)d_in[12];
    const float* pb4    = (const float*)d_in[13];
    const float* ranges = (const float*)d_in[14];
    const float* ua     = (const float*)d_in[15];
    const float* ub     = (const float*)d_in[16];
    const float* gum    = (const float*)d_in[17];

    float* out       = (float*)d_out;
    float* out_truth = out;                       // B*N
    float* out_xcf   = out + 524288;              // B*544
    float* out_P     = out + 4980736;             // B*N
    float* out_W     = out + 5505024;              // B*D

    // workspace layout (16B-aligned sections)
    char* w = (char*)d_ws;
    size_t off = 0;
    __hip_bfloat16* A0   = (__hip_bfloat16*)(w + off); off += (size_t)B_DIM * D_DIM * 2;
    __hip_bfloat16* act1 = (__hip_bfloat16*)(w + off); off += (size_t)B_DIM * 2048 * 2;
    __hip_bfloat16* actB = (__hip_bfloat16*)(w + off); off += (size_t)B_DIM * HP * 2;
    __hip_bfloat16* actC = (__hip_bfloat16*)(w + off); off += (size_t)B_DIM * HP * 2;
    __hip_bfloat16* Wcat = (__hip_bfloat16*)(w + off); off += (size_t)2048 * D_DIM * 2;
    __hip_bfloat16* w2t  = (__hip_bfloat16*)(w + off); off += (size_t)128 * HS * 2;
    __hip_bfloat16* p2t  = (__hip_bfloat16*)(w + off); off += (size_t)HP * HP * 2;
    __hip_bfloat16* p3t  = (__hip_bfloat16*)(w + off); off += (size_t)HP * HP * 2;
    __hip_bfloat16* p4t  = (__hip_bfloat16*)(w + off); off += (size_t)D_DIM * HP * 2;
    float* rmean         = (float*)(w + off);          off += 512 * 4;
    float* bcat          = (float*)(w + off);          off += 2048 * 4;
    if (ws_size < off) return;

    PrepArgs pa;
    pa.src[0] = sel_w1; pa.dst[0] = Wcat;               pa.Nsrc[0] = HS;    pa.Npad[0] = 1024;
    pa.src[1] = pw1;    pa.dst[1] = Wcat + 1024 * 1024; pa.Nsrc[1] = HP;    pa.Npad[1] = 1024;
    pa.src[2] = sel_w2; pa.dst[2] = w2t;                pa.Nsrc[2] = N_DIM; pa.Npad[2] = 128;
    pa.src[3] = pw2;    pa.dst[3] = p2t;                pa.Nsrc[3] = HP;    pa.Npad[3] = 1024;
    pa.src[4] = pw3;    pa.dst[4] = p3t;                pa.Nsrc[4] = HP;    pa.Npad[4] = 1024;
    pa.src[5] = pw4;    pa.dst[5] = p4t;                pa.Nsrc[5] = D_DIM; pa.Npad[5] = 1024;
    pa.ranges = ranges; pa.rmean = rmean;
    pa.b1 = sel_b1; pa.b2 = pb1; pa.bcat = bcat;
    pa.x = x; pa.xbf = A0;

    prep_kernel<<<dim3(32, 32, 8), dim3(32, 8), 0, stream>>>(pa);

    // Layer 1 fused (sel + policy): A0 x Wcat^T -> act1 (B x 2048), relu
    gemm8<1><<<dim3(16, 64), 512, 0, stream>>>(A0, Wcat, bcat, nullptr, act1,
                                               D_DIM, 2048, 2048, D_DIM);
    // p2 GEMM + sel layer-2 (fused launch) — 576 blocks
    gemm8_fused23<<<dim3(9, 64), 512, 0, stream>>>(act1, p2t, pb2, actB, w2t,
                                                   sel_b2, out_P);
    // p3 — 512 blocks
    gemm8<1><<<dim3(8, 64), 512, 0, stream>>>(actB, p3t, pb3, nullptr, actC,
                                              HP, HP, HP, HP);
    // p4 -> W + fused finalize — 512 blocks
    FinArgs fa;
    fa.x = x; fa.truth = truth; fa.ua = ua; fa.ub = ub; fa.gum = gum;
    fa.rmean = rmean; fa.P = out_P;
    fa.out_truth = out_truth; fa.out_xcf = out_xcf;
    gemm8_final<<<dim3(8, 64), 512, 0, stream>>>(actC, p4t, pb4, out_W,
                                                 HP, HP, fa);
}